// Round 1
// baseline (3453.402 us; speedup 1.0000x reference)
//
#include <hip/hip_runtime.h>

#define BB 32
#define TT 2048
#define DD 256
#define HH 256
#define AA 128
#define CC 4367
#define NSTEPS 22

__device__ __forceinline__ float tanh_fast(float u) {
  float e = __expf(2.0f * u);
  return 1.0f - 2.0f / (e + 1.0f);   // exact at +/-inf, ~1e-6 abs err
}
__device__ __forceinline__ float sigmoid_fast(float u) {
  return 1.0f / (1.0f + __expf(-u));
}

// ---------- xW[b,t,a] = sum_d x[b,t,d] * Wx[d,a]  (fp32, vector ALU) ----------
// Block: 256 threads, 32 rows of the flattened [B*T, D] matrix, all 128 cols.
// x rows staged in LDS, read back as float4 broadcasts (cheap, same-addr).
__global__ __launch_bounds__(256) void xw_kernel(const float* __restrict__ x,
                                                 const float* __restrict__ Wx,
                                                 float* __restrict__ xW) {
  __shared__ __align__(16) float sx[32 * DD];
  const int tid = threadIdx.x;
  const int r0 = blockIdx.x * 32;
  {
    const float4* src = (const float4*)(x + (size_t)r0 * DD);
    float4* dst = (float4*)sx;
#pragma unroll
    for (int i = 0; i < 8; ++i) dst[tid + 256 * i] = src[tid + 256 * i];
  }
  __syncthreads();
  const int a = tid & (AA - 1);
  const int rg = (tid >> 7) * 16;  // 0 or 16: which 16-row group
  float acc[16];
#pragma unroll
  for (int r = 0; r < 16; ++r) acc[r] = 0.f;
  const float4* sxr = (const float4*)sx;
  for (int k4 = 0; k4 < DD / 4; ++k4) {
    const float* wp = Wx + k4 * 4 * AA + a;
    float w0 = wp[0], w1 = wp[AA], w2 = wp[2 * AA], w3 = wp[3 * AA];
#pragma unroll
    for (int r = 0; r < 16; ++r) {
      float4 xv = sxr[(rg + r) * (DD / 4) + k4];
      acc[r] = fmaf(xv.w, w3, fmaf(xv.z, w2, fmaf(xv.y, w1, fmaf(xv.x, w0, acc[r]))));
    }
  }
#pragma unroll
  for (int r = 0; r < 16; ++r) xW[(size_t)(r0 + rg + r) * AA + a] = acc[r];
}

// ---------- one decoder step ----------
// K_step(s), s = 0..22. Grid (8 chunks, 32 batch), 256 threads.
//   1. h_cur = (s==0) ? 0 : GRU(ctx_prev/den_prev, h_prev)   [redundant per chunk]
//   2. if s>=1: logits_{s-1} = h_cur @ W_cls^T + b_cls       [this chunk's c-slice]
//   3. if s<22: attention with h_cur over this chunk's 256 t's,
//      atomicAdd partial (sum_t w*x) and sum_t w into this step's accumulators.
// No softmax max-pass: |e| <= ||v||_1 ~ 5, exp cannot overflow.
__global__ __launch_bounds__(256) void step_kernel(
    const float* __restrict__ x, const float* __restrict__ xW,
    const float* __restrict__ Wh, const float* __restrict__ v,
    const float* __restrict__ W_ih, const float* __restrict__ W_hh,
    const float* __restrict__ b_ih, const float* __restrict__ b_hh,
    const float* __restrict__ W_cls, const float* __restrict__ b_cls,
    const float* __restrict__ ctx_prev, const float* __restrict__ den_prev,
    float* __restrict__ ctx_out, float* __restrict__ den_out,
    const float* __restrict__ h_prev, float* __restrict__ h_out,
    float* __restrict__ out, int s) {
  const int tid = threadIdx.x;
  const int chunk = blockIdx.x;  // 0..7  (t-chunk of 256, and logits c-slice)
  const int b = blockIdx.y;      // 0..31
  __shared__ __align__(16) float sh_h[HH];
  __shared__ __align__(16) float sh_ctx[DD];
  __shared__ __align__(16) float sh_hp[HH];
  __shared__ __align__(16) float sh_hWh[AA];
  __shared__ __align__(16) float sh_w[256];
  __shared__ float sh_v[AA];

  if (tid < AA) sh_v[tid] = v[tid];

  // ---- Phase 1: h_cur ----
  if (s == 0) {
    sh_h[tid] = 0.f;
    if (chunk == 0) h_out[b * HH + tid] = 0.f;
  } else {
    const float inv_den = 1.0f / den_prev[b];
    sh_ctx[tid] = ctx_prev[b * DD + tid] * inv_den;
    sh_hp[tid] = h_prev[b * HH + tid];
    __syncthreads();
    float gr = b_ih[tid], gz = b_ih[HH + tid], gn = b_ih[2 * HH + tid];
    float hr = b_hh[tid], hz = b_hh[HH + tid], hn = b_hh[2 * HH + tid];
    const float4* wir = (const float4*)(W_ih + (size_t)tid * DD);
    const float4* wiz = (const float4*)(W_ih + (size_t)(HH + tid) * DD);
    const float4* win = (const float4*)(W_ih + (size_t)(2 * HH + tid) * DD);
    const float4* whr = (const float4*)(W_hh + (size_t)tid * HH);
    const float4* whz = (const float4*)(W_hh + (size_t)(HH + tid) * HH);
    const float4* whn = (const float4*)(W_hh + (size_t)(2 * HH + tid) * HH);
    const float4* c4p = (const float4*)sh_ctx;
    const float4* h4p = (const float4*)sh_hp;
#pragma unroll 4
    for (int k = 0; k < DD / 4; ++k) {
      float4 c4 = c4p[k], h4 = h4p[k], wv;
      wv = wir[k]; gr += c4.x * wv.x + c4.y * wv.y + c4.z * wv.z + c4.w * wv.w;
      wv = wiz[k]; gz += c4.x * wv.x + c4.y * wv.y + c4.z * wv.z + c4.w * wv.w;
      wv = win[k]; gn += c4.x * wv.x + c4.y * wv.y + c4.z * wv.z + c4.w * wv.w;
      wv = whr[k]; hr += h4.x * wv.x + h4.y * wv.y + h4.z * wv.z + h4.w * wv.w;
      wv = whz[k]; hz += h4.x * wv.x + h4.y * wv.y + h4.z * wv.z + h4.w * wv.w;
      wv = whn[k]; hn += h4.x * wv.x + h4.y * wv.y + h4.z * wv.z + h4.w * wv.w;
    }
    float r = sigmoid_fast(gr + hr);
    float z = sigmoid_fast(gz + hz);
    float n = tanh_fast(gn + r * hn);
    float hv = (1.f - z) * n + z * sh_hp[tid];
    sh_h[tid] = hv;
    if (chunk == 0) h_out[b * HH + tid] = hv;
  }
  __syncthreads();

  // ---- Phase 2: logits for step s-1 (uses h_cur = h_s) ----
  if (s >= 1) {
    const int cbeg = chunk * 546;
    const int cend = min(cbeg + 546, CC);
    const float4* h4p = (const float4*)sh_h;
    for (int c = cbeg + tid; c < cend; c += 256) {
      const float4* wr = (const float4*)(W_cls + (size_t)c * HH);
      float acc = b_cls[c];
#pragma unroll 8
      for (int k = 0; k < HH / 4; ++k) {
        float4 wv = wr[k], h4 = h4p[k];
        acc += h4.x * wv.x + h4.y * wv.y + h4.z * wv.z + h4.w * wv.w;
      }
      out[((size_t)b * NSTEPS + (s - 1)) * CC + c] = acc;
    }
  }

  // ---- Phase 3: attention for step s ----
  if (s < NSTEPS) {
    if (tid < AA) {  // hWh[b, tid] = sum_k h[k] * Wh[k, tid]
      float acc = 0.f;
#pragma unroll 4
      for (int k = 0; k < HH; ++k) acc = fmaf(sh_h[k], Wh[k * AA + tid], acc);
      sh_hWh[tid] = acc;
    }
    __syncthreads();
    const int lane = tid & 63;
    const int wv = tid >> 6;
    const int t0 = chunk * 256;
    const float hw0 = sh_hWh[lane], hw1 = sh_hWh[lane + 64];
    const float v0 = sh_v[lane], v1 = sh_v[lane + 64];
    // each of 4 waves handles t = t0 + 4*i + wv
    for (int i = 0; i < 64; ++i) {
      const int tt = i * 4 + wv;
      const float* p = xW + ((size_t)b * TT + t0 + tt) * AA;
      float s0 = tanh_fast(p[lane] + hw0) * v0 + tanh_fast(p[lane + 64] + hw1) * v1;
#pragma unroll
      for (int off = 32; off > 0; off >>= 1) s0 += __shfl_down(s0, off, 64);
      if (lane == 0) sh_w[tt] = __expf(s0);
    }
    __syncthreads();
    // ctx partial: thread tid = d, loop over this chunk's 256 t's
    float cacc = 0.f;
    const float* xb = x + ((size_t)b * TT + t0) * DD + tid;
#pragma unroll 8
    for (int j = 0; j < 256; ++j) cacc = fmaf(sh_w[j], xb[(size_t)j * DD], cacc);
    atomicAdd(&ctx_out[b * DD + tid], cacc);
    if (tid < 64) {
      float ds = sh_w[tid] + sh_w[tid + 64] + sh_w[tid + 128] + sh_w[tid + 192];
#pragma unroll
      for (int off = 32; off > 0; off >>= 1) ds += __shfl_down(ds, off, 64);
      if (tid == 0) atomicAdd(&den_out[b], ds);
    }
  }
}

extern "C" void kernel_launch(void* const* d_in, const int* in_sizes, int n_in,
                              void* d_out, int out_size, void* d_ws, size_t ws_size,
                              hipStream_t stream) {
  const float* x     = (const float*)d_in[0];
  const float* Wx    = (const float*)d_in[1];
  const float* Wh    = (const float*)d_in[2];
  const float* v     = (const float*)d_in[3];
  const float* W_ih  = (const float*)d_in[4];
  const float* W_hh  = (const float*)d_in[5];
  const float* b_ih  = (const float*)d_in[6];
  const float* b_hh  = (const float*)d_in[7];
  const float* W_cls = (const float*)d_in[8];
  const float* b_cls = (const float*)d_in[9];
  float* out = (float*)d_out;

  // workspace layout (floats): xW | 23x ctxacc | 23x den | 2x hbuf  (~32.8 MiB)
  float* xW = (float*)d_ws;                              // B*T*A
  float* ctxacc = xW + (size_t)BB * TT * AA;             // 23 * B * D
  float* den = ctxacc + (size_t)23 * BB * DD;            // 23 * B
  float* hbuf = den + 23 * BB;                           // 2 * B * H

  hipMemsetAsync(ctxacc, 0, (size_t)(23 * BB * DD + 23 * BB) * sizeof(float), stream);
  xw_kernel<<<dim3((BB * TT) / 32), 256, 0, stream>>>(x, Wx, xW);
  for (int s = 0; s <= NSTEPS; ++s) {
    const float* ctx_p = (s > 0) ? ctxacc + (size_t)(s - 1) * BB * DD : nullptr;
    const float* den_p = (s > 0) ? den + (s - 1) * BB : nullptr;
    float* ctx_o = (s < NSTEPS) ? ctxacc + (size_t)s * BB * DD : nullptr;
    float* den_o = (s < NSTEPS) ? den + s * BB : nullptr;
    const float* h_p = hbuf + (size_t)((s + 1) & 1) * BB * HH;
    float* h_o = hbuf + (size_t)(s & 1) * BB * HH;
    step_kernel<<<dim3(8, 32), 256, 0, stream>>>(
        x, xW, Wh, v, W_ih, W_hh, b_ih, b_hh, W_cls, b_cls,
        ctx_p, den_p, ctx_o, den_o, h_p, h_o, out, s);
  }
}

// Round 3
// 1320.945 us; speedup vs baseline: 2.6143x; 2.6143x over previous
//
#include <hip/hip_runtime.h>

#define BB 32
#define TT 2048
#define DD 256
#define HH 256
#define AA 128
#define CC 4367
#define CLS_LD 4480   // 35*128, padded WclsT leading dim
#define NSTEPS 22

typedef unsigned short ushortT;

__device__ __forceinline__ float tanh_fast(float u) {
  float e = __expf(2.0f * u);
  return 1.0f - 2.0f / (e + 1.0f);
}
__device__ __forceinline__ float sigmoid_fast(float u) {
  return 1.0f / (1.0f + __expf(-u));
}
__device__ __forceinline__ ushortT f2bf(float f) {
  unsigned int u = __float_as_uint(f);
  unsigned int r = (u + 0x7FFFu + ((u >> 16) & 1u)) >> 16;
  return (ushortT)r;
}
__device__ __forceinline__ float bf2f(ushortT v) {
  return __uint_as_float(((unsigned int)v) << 16);
}

// ---------- prep: transpose W_ih, W_hh (768x256 -> 256x768) and W_cls (4367x256 -> 256x4480) ----------
__global__ __launch_bounds__(256) void trans_kernel(
    const float* __restrict__ W_ih, const float* __restrict__ W_hh,
    const float* __restrict__ W_cls,
    float* __restrict__ WihT, float* __restrict__ WhhT, float* __restrict__ WclsT) {
  int blk = blockIdx.x;
  const float* src; float* dst; int R, ldT;
  if (blk < 192)      { src = W_ih;  dst = WihT;  R = 768;  ldT = 768; }
  else if (blk < 384) { blk -= 192; src = W_hh;  dst = WhhT;  R = 768;  ldT = 768; }
  else                { blk -= 384; src = W_cls; dst = WclsT; R = 4367; ldT = CLS_LD; }
  const int C = 256;
  int i0 = (blk >> 3) * 32;       // row tile (8 col-tiles per row)
  int j0 = (blk & 7) * 32;        // col tile
  __shared__ float tile[32][33];
  int li = threadIdx.x >> 5, lj = threadIdx.x & 31;
#pragma unroll
  for (int k = 0; k < 4; ++k) {
    int i = i0 + li + k * 8;
    if (i < R) tile[li + k * 8][lj] = src[(size_t)i * C + j0 + lj];
  }
  __syncthreads();
#pragma unroll
  for (int k = 0; k < 4; ++k) {
    int j = j0 + li + k * 8;      // output row (= src col)
    int i = i0 + lj;              // output col (= src row)
    if (i < R) dst[(size_t)j * ldT + i] = tile[lj][li + k * 8];
  }
}

// ---------- prep: xW = x@Wx (fp32 compute), emit x_bf [B,T,D] bf16 and xWT_bf [B,A,T] bf16 ----------
__global__ __launch_bounds__(256) void xw_kernel(const float* __restrict__ x,
                                                 const float* __restrict__ Wx,
                                                 ushortT* __restrict__ x_bf,
                                                 ushortT* __restrict__ xWT_bf) {
  __shared__ __align__(16) float sx[32 * DD];   // 32 KB
  const int tid = threadIdx.x;
  const int r0 = blockIdx.x * 32;               // flat row in [B*T]
  {
    const float4* src = (const float4*)(x + (size_t)r0 * DD);
    float4* dst = (float4*)sx;
#pragma unroll
    for (int i = 0; i < 8; ++i) dst[tid + 256 * i] = src[tid + 256 * i];
  }
  __syncthreads();
  // write x_bf tile (ushort2-coalesced)
  {
    ushort2* xb2 = (ushort2*)(x_bf + (size_t)r0 * DD);
    int col2 = tid & 127, rr = tid >> 7;
#pragma unroll
    for (int i = 0; i < 16; ++i) {
      int row = 2 * i + rr;
      ushort2 u;
      u.x = f2bf(sx[row * DD + col2 * 2]);
      u.y = f2bf(sx[row * DD + col2 * 2 + 1]);
      xb2[row * 128 + col2] = u;
    }
  }
  // compute xW tile
  const int a = tid & (AA - 1);
  const int rg = (tid >> 7) * 16;
  float acc[16];
#pragma unroll
  for (int r = 0; r < 16; ++r) acc[r] = 0.f;
  const float4* sxr = (const float4*)sx;
  for (int k4 = 0; k4 < DD / 4; ++k4) {
    const float* wp = Wx + k4 * 4 * AA + a;
    float w0 = wp[0], w1 = wp[AA], w2 = wp[2 * AA], w3 = wp[3 * AA];
#pragma unroll
    for (int r = 0; r < 16; ++r) {
      float4 xv = sxr[(rg + r) * (DD / 4) + k4];
      acc[r] = fmaf(xv.w, w3, fmaf(xv.z, w2, fmaf(xv.y, w1, fmaf(xv.x, w0, acc[r]))));
    }
  }
  __syncthreads();                  // done reading sx; reuse as bf16 transpose buffer
  ushortT* sT = (ushortT*)sx;       // [128 a][33] (t_local stride 33)
#pragma unroll
  for (int r = 0; r < 16; ++r) sT[a * 33 + rg + r] = f2bf(acc[r]);
  __syncthreads();
  // write xWT_bf[b][a][t0..t0+31]
  const int b = r0 >> 11, t0 = r0 & (TT - 1);
  ushort2* out2 = (ushort2*)xWT_bf;
  const size_t base2 = (size_t)b * (AA * TT / 2) + (t0 >> 1);
#pragma unroll
  for (int j = 0; j < 8; ++j) {
    int idx = j * 256 + tid;
    int ao = idx >> 4, t2 = idx & 15;
    ushort2 u;
    u.x = sT[ao * 33 + 2 * t2];
    u.y = sT[ao * 33 + 2 * t2 + 1];
    out2[base2 + (size_t)ao * (TT / 2) + t2] = u;
  }
}

// ---------- per-step GRU + hWh (grid BB blocks x 768 threads) ----------
// NOTE: takes BASE ctx_acc/den pointers and indexes by s itself (round-2 bug
// was double-offsetting: host offset + kernel offset -> read zero den -> 1/0 -> NaN).
__global__ __launch_bounds__(768) void gru_kernel(
    const float* __restrict__ ctx_acc, const float* __restrict__ den,
    const float* __restrict__ WihT, const float* __restrict__ WhhT,
    const float* __restrict__ Wh,
    const float* __restrict__ b_ih, const float* __restrict__ b_hh,
    float* __restrict__ hall, float* __restrict__ hWh_buf, int s) {
  const int b = blockIdx.x, tid = threadIdx.x;
  __shared__ float sc[DD], sp[HH], gi[768], gh[768], sh[HH], hp4[4 * AA];
  if (tid < DD) {
    float invd = 1.0f / den[(s - 1) * BB + b];
    sc[tid] = ctx_acc[((size_t)(s - 1) * BB + b) * DD + tid] * invd;
    sp[tid] = (s == 1) ? 0.f : hall[((size_t)(s - 2) * BB + b) * HH + tid];
  }
  __syncthreads();
  float gacc = b_ih[tid], hacc = b_hh[tid];
#pragma unroll 4
  for (int d = 0; d < DD; ++d) {
    gacc = fmaf(sc[d], WihT[(size_t)d * 768 + tid], gacc);
    hacc = fmaf(sp[d], WhhT[(size_t)d * 768 + tid], hacc);
  }
  gi[tid] = gacc; gh[tid] = hacc;
  __syncthreads();
  if (tid < HH) {
    float r = sigmoid_fast(gi[tid] + gh[tid]);
    float z = sigmoid_fast(gi[HH + tid] + gh[HH + tid]);
    float n = tanh_fast(gi[2 * HH + tid] + r * gh[2 * HH + tid]);
    float hv = (1.f - z) * n + z * sp[tid];
    sh[tid] = hv;
    hall[((size_t)(s - 1) * BB + b) * HH + tid] = hv;
  }
  __syncthreads();
  if (tid < 512) {  // hWh: 4 k-groups of 64
    int a = tid & (AA - 1), kg = tid >> 7;
    float acc = 0.f;
#pragma unroll 4
    for (int k = kg * 64; k < kg * 64 + 64; ++k)
      acc = fmaf(sh[k], Wh[k * AA + a], acc);
    hp4[kg * AA + a] = acc;
  }
  __syncthreads();
  if (tid < AA)
    hWh_buf[b * AA + tid] = hp4[tid] + hp4[AA + tid] + hp4[2 * AA + tid] + hp4[3 * AA + tid];
}

// ---------- per-step attention: scores + ctx partials (grid 32 x 32, 256 thr) ----------
__global__ __launch_bounds__(256) void att_kernel(
    const ushortT* __restrict__ x_bf, const ushortT* __restrict__ xWT_bf,
    const float* __restrict__ hWh_buf, const float* __restrict__ v,
    float* __restrict__ ctx_out, float* __restrict__ den_out) {
  const int tid = threadIdx.x;
  const int chunk = blockIdx.x;   // 0..31, 64 t's each
  const int b = blockIdx.y;
  const int t0 = chunk * 64;
  __shared__ float sh_hWh[AA], sh_v[AA];
  __shared__ float sh_part[8 * 64];
  __shared__ float sh_w[64];
  __shared__ __align__(16) float sh_ctx[4 * DD];
  if (tid < AA) { sh_hWh[tid] = hWh_buf[b * AA + tid]; sh_v[tid] = v[tid]; }
  __syncthreads();
  // Phase A: scores. thread = (q = a-group of 16, tp = t-pair)
  {
    const int q = tid >> 5, tp = tid & 31;
    float p0 = 0.f, p1 = 0.f;
    const ushort2* xw2 = (const ushort2*)xWT_bf;
    const size_t base = (size_t)b * (AA * TT / 2) + (t0 >> 1) + tp;
#pragma unroll 4
    for (int i = 0; i < 16; ++i) {
      int a = q * 16 + i;
      ushort2 u = xw2[base + (size_t)a * (TT / 2)];
      float hwa = sh_hWh[a], va = sh_v[a];
      p0 = fmaf(tanh_fast(bf2f(u.x) + hwa), va, p0);
      p1 = fmaf(tanh_fast(bf2f(u.y) + hwa), va, p1);
    }
    sh_part[q * 64 + 2 * tp] = p0;
    sh_part[q * 64 + 2 * tp + 1] = p1;
  }
  __syncthreads();
  if (tid < 64) {
    float e = 0.f;
#pragma unroll
    for (int q = 0; q < 8; ++q) e += sh_part[q * 64 + tid];
    sh_w[tid] = __expf(e);   // |e| <= ||v||_1 ~ 5: no overflow, no max-pass needed
  }
  __syncthreads();
  // Phase B: ctx partials. wave j4 handles t = t0 + 4*j + j4; lane dq covers 4 d's.
  {
    const int j4 = tid >> 6, dq = tid & 63;
    float4 acc = {0.f, 0.f, 0.f, 0.f};
    const ushort4* xb4 = (const ushort4*)x_bf;
#pragma unroll 4
    for (int j = 0; j < 16; ++j) {
      int t = t0 + j * 4 + j4;
      float w = sh_w[j * 4 + j4];
      ushort4 u = xb4[((size_t)(b * TT + t) * DD >> 2) + dq];
      acc.x = fmaf(w, bf2f(u.x), acc.x);
      acc.y = fmaf(w, bf2f(u.y), acc.y);
      acc.z = fmaf(w, bf2f(u.z), acc.z);
      acc.w = fmaf(w, bf2f(u.w), acc.w);
    }
    ((float4*)sh_ctx)[j4 * 64 + dq] = acc;
  }
  __syncthreads();
  {
    float sum = sh_ctx[tid] + sh_ctx[DD + tid] + sh_ctx[2 * DD + tid] + sh_ctx[3 * DD + tid];
    atomicAdd(&ctx_out[b * DD + tid], sum);
  }
  if (tid < 64) {
    float ds = sh_w[tid];
#pragma unroll
    for (int off = 32; off > 0; off >>= 1) ds += __shfl_down(ds, off, 64);
    if (tid == 0) atomicAdd(&den_out[b], ds);
  }
}

// ---------- final: all logits out[b,s,c] = hall[s,b,:] @ W_cls^T + b_cls ----------
__global__ __launch_bounds__(256) void cls_kernel(
    const float* __restrict__ hall, const float* __restrict__ WclsT,
    const float* __restrict__ b_cls, float* __restrict__ out) {
  const int tid = threadIdx.x;
  const int c0 = blockIdx.x * 128;   // 35 tiles
  const int r0 = blockIdx.y * 32;    // 22 tiles of (b,s) rows
  const int cq = tid & 31, rg = tid >> 5;
  const int c = c0 + cq * 4;
  __shared__ __align__(16) float shh[32 * HH];   // 32 KB
  {
    const float4* hsrc = (const float4*)(hall + (size_t)r0 * HH);
    float4* hdst = (float4*)shh;
#pragma unroll
    for (int i = 0; i < 8; ++i) hdst[tid + 256 * i] = hsrc[tid + 256 * i];
  }
  __syncthreads();
  float acc[4][4];
#pragma unroll
  for (int j = 0; j < 4; ++j)
#pragma unroll
    for (int l = 0; l < 4; ++l) acc[j][l] = 0.f;
  for (int k = 0; k < HH; ++k) {
    float4 w4 = *(const float4*)(WclsT + (size_t)k * CLS_LD + c);
    float h0 = shh[(rg * 4 + 0) * HH + k];
    float h1 = shh[(rg * 4 + 1) * HH + k];
    float h2 = shh[(rg * 4 + 2) * HH + k];
    float h3 = shh[(rg * 4 + 3) * HH + k];
    acc[0][0] = fmaf(h0, w4.x, acc[0][0]); acc[0][1] = fmaf(h0, w4.y, acc[0][1]);
    acc[0][2] = fmaf(h0, w4.z, acc[0][2]); acc[0][3] = fmaf(h0, w4.w, acc[0][3]);
    acc[1][0] = fmaf(h1, w4.x, acc[1][0]); acc[1][1] = fmaf(h1, w4.y, acc[1][1]);
    acc[1][2] = fmaf(h1, w4.z, acc[1][2]); acc[1][3] = fmaf(h1, w4.w, acc[1][3]);
    acc[2][0] = fmaf(h2, w4.x, acc[2][0]); acc[2][1] = fmaf(h2, w4.y, acc[2][1]);
    acc[2][2] = fmaf(h2, w4.z, acc[2][2]); acc[2][3] = fmaf(h2, w4.w, acc[2][3]);
    acc[3][0] = fmaf(h3, w4.x, acc[3][0]); acc[3][1] = fmaf(h3, w4.y, acc[3][1]);
    acc[3][2] = fmaf(h3, w4.z, acc[3][2]); acc[3][3] = fmaf(h3, w4.w, acc[3][3]);
  }
#pragma unroll
  for (int j = 0; j < 4; ++j) {
    int row = r0 + rg * 4 + j;        // row = (s)*BB + b
    int bb = row & (BB - 1), st = row >> 5;
    size_t obase = ((size_t)bb * NSTEPS + st) * CC;
#pragma unroll
    for (int l = 0; l < 4; ++l) {
      int cc = c + l;
      if (cc < CC) out[obase + cc] = acc[j][l] + b_cls[cc];
    }
  }
}

extern "C" void kernel_launch(void* const* d_in, const int* in_sizes, int n_in,
                              void* d_out, int out_size, void* d_ws, size_t ws_size,
                              hipStream_t stream) {
  const float* x     = (const float*)d_in[0];
  const float* Wx    = (const float*)d_in[1];
  const float* Wh    = (const float*)d_in[2];
  const float* v     = (const float*)d_in[3];
  const float* W_ih  = (const float*)d_in[4];
  const float* W_hh  = (const float*)d_in[5];
  const float* b_ih  = (const float*)d_in[6];
  const float* b_hh  = (const float*)d_in[7];
  const float* W_cls = (const float*)d_in[8];
  const float* b_cls = (const float*)d_in[9];
  float* out = (float*)d_out;

  // workspace layout (floats first, then bf16 arrays) -- ~55.3 MiB total
  float* ctx_acc = (float*)d_ws;                     // 22*32*256 = 180224
  float* den     = ctx_acc + (size_t)NSTEPS * BB * DD;      // 704
  float* hWh_buf = den + NSTEPS * BB;                       // 32*128 = 4096
  float* hall    = hWh_buf + BB * AA;                       // 704*256 = 180224
  float* WihT    = hall + (size_t)NSTEPS * BB * HH;         // 196608
  float* WhhT    = WihT + 256 * 768;                        // 196608
  float* WclsT   = WhhT + 256 * 768;                        // 256*4480 = 1146880
  ushortT* x_bf  = (ushortT*)(WclsT + (size_t)256 * CLS_LD);    // B*T*D
  ushortT* xWT   = x_bf + (size_t)BB * TT * DD;                 // B*A*T

  // zero ctx accumulators + dens + step-0 hWh (contiguous)
  hipMemsetAsync(ctx_acc, 0, (size_t)(NSTEPS * BB * DD + NSTEPS * BB + BB * AA) * sizeof(float), stream);
  trans_kernel<<<384 + 1096, 256, 0, stream>>>(W_ih, W_hh, W_cls, WihT, WhhT, WclsT);
  xw_kernel<<<(BB * TT) / 32, 256, 0, stream>>>(x, Wx, x_bf, xWT);

  att_kernel<<<dim3(32, BB), 256, 0, stream>>>(x_bf, xWT, hWh_buf, v,
                                               ctx_acc, den);
  for (int s = 1; s < NSTEPS; ++s) {
    gru_kernel<<<BB, 768, 0, stream>>>(ctx_acc, den,
                                       WihT, WhhT, Wh, b_ih, b_hh, hall, hWh_buf, s);
    att_kernel<<<dim3(32, BB), 256, 0, stream>>>(x_bf, xWT, hWh_buf, v,
                                                 ctx_acc + (size_t)s * BB * DD, den + s * BB);
  }
  gru_kernel<<<BB, 768, 0, stream>>>(ctx_acc, den,
                                     WihT, WhhT, Wh, b_ih, b_hh, hall, hWh_buf, NSTEPS);
  cls_kernel<<<dim3(35, 22), 256, 0, stream>>>(hall, WclsT, b_cls, out);
}

// Round 4
// 1001.901 us; speedup vs baseline: 3.4468x; 1.3184x over previous
//
#include <hip/hip_runtime.h>

#define BB 32
#define TT 2048
#define DD 256
#define HH 256
#define AA 128
#define CC 4367
#define CLS_LD 4480   // 35*128, padded WclsT leading dim
#define NSTEPS 22

typedef unsigned short ushortT;
typedef unsigned int uintT;
using frag8 = __attribute__((ext_vector_type(8))) short;
using f32x4 = __attribute__((ext_vector_type(4))) float;

__device__ __forceinline__ float tanh_fast(float u) {
  float e = __expf(2.0f * u);
  return 1.0f - 2.0f / (e + 1.0f);
}
__device__ __forceinline__ float sigmoid_fast(float u) {
  return 1.0f / (1.0f + __expf(-u));
}
__device__ __forceinline__ ushortT f2bf(float f) {
  unsigned int u = __float_as_uint(f);
  unsigned int r = (u + 0x7FFFu + ((u >> 16) & 1u)) >> 16;
  return (ushortT)r;
}
__device__ __forceinline__ float bf2f(ushortT v) {
  return __uint_as_float(((unsigned int)v) << 16);
}

// ---------- prep: WclsT fp32 [256][4480] and WxT_bf bf16 [128][256] ----------
__global__ __launch_bounds__(256) void trans_kernel(
    const float* __restrict__ Wx, const float* __restrict__ W_cls,
    float* __restrict__ WclsT, ushortT* __restrict__ WxT_bf) {
  int blk = blockIdx.x;
  __shared__ float tile[32][33];
  const int li = threadIdx.x >> 5, lj = threadIdx.x & 31;
  if (blk < 1096) {  // W_cls 4367x256 -> WclsT 256x4480
    int i0 = (blk >> 3) * 32, j0 = (blk & 7) * 32;
#pragma unroll
    for (int k = 0; k < 4; ++k) {
      int i = i0 + li + k * 8;
      if (i < CC) tile[li + k * 8][lj] = W_cls[(size_t)i * 256 + j0 + lj];
    }
    __syncthreads();
#pragma unroll
    for (int k = 0; k < 4; ++k) {
      int j = j0 + li + k * 8, i = i0 + lj;
      if (i < CC) WclsT[(size_t)j * CLS_LD + i] = tile[lj][li + k * 8];
    }
  } else {  // Wx 256x128 -> WxT_bf 128x256
    blk -= 1096;  // 0..31
    int i0 = (blk >> 2) * 32, j0 = (blk & 3) * 32;
#pragma unroll
    for (int k = 0; k < 4; ++k)
      tile[li + k * 8][lj] = Wx[(size_t)(i0 + li + k * 8) * 128 + j0 + lj];
    __syncthreads();
#pragma unroll
    for (int k = 0; k < 4; ++k) {
      int j = j0 + li + k * 8;
      WxT_bf[(size_t)j * 256 + i0 + lj] = f2bf(tile[lj][li + k * 8]);
    }
  }
}

// ---------- xW via MFMA bf16: block = 128 rows of [BT,256] x [256,128] ----------
// Emits x_bf [BT][256] bf16 (during staging) and xWT [B][A][T] bf16 (transposed).
// Frag layouts (m89/m91/m120-verified): A: lane l -> A[m=l&15][k=(l>>4)*8+j];
// B: lane l -> B[k=(l>>4)*8+j][n=l&15]; D: lane l, reg r -> D[m=(l>>4)*4+r][n=l&15].
__global__ __launch_bounds__(256) void xw_mfma(
    const float* __restrict__ x, const ushortT* __restrict__ WxT_bf,
    ushortT* __restrict__ x_bf, ushortT* __restrict__ xWT) {
  __shared__ ushortT lds[2 * 128 * 72];  // sX | sW staging; reused as sT[128][136]
#define SX(r, c) lds[(r) * 72 + (c)]
#define SW(r, c) lds[128 * 72 + (r) * 72 + (c)]
#define ST(a, m) lds[(a) * 136 + (m)]
  const int tid = threadIdx.x;
  const int lane = tid & 63, w = tid >> 6;
  const int l15 = lane & 15, quad = lane >> 4;
  const int r0 = blockIdx.x * 128;
  const int bb = blockIdx.x >> 4, t0 = (blockIdx.x & 15) * 128;
  const int row = tid >> 1, half = tid & 1;

  f32x4 acc[2][8];
#pragma unroll
  for (int mt = 0; mt < 2; ++mt)
#pragma unroll
    for (int nt = 0; nt < 8; ++nt) acc[mt][nt] = (f32x4){0.f, 0.f, 0.f, 0.f};

  for (int kk0 = 0; kk0 < 256; kk0 += 64) {
    // stage x (fp32 -> bf16) + write-through to x_bf
    {
      const float4* xp = (const float4*)(x + (size_t)(r0 + row) * DD + kk0 + half * 32);
      uint4 pk[4];
#pragma unroll
      for (int i = 0; i < 4; ++i) {
        float4 f0 = xp[2 * i], f1 = xp[2 * i + 1];
        pk[i].x = (uintT)f2bf(f0.x) | ((uintT)f2bf(f0.y) << 16);
        pk[i].y = (uintT)f2bf(f0.z) | ((uintT)f2bf(f0.w) << 16);
        pk[i].z = (uintT)f2bf(f1.x) | ((uintT)f2bf(f1.y) << 16);
        pk[i].w = (uintT)f2bf(f1.z) | ((uintT)f2bf(f1.w) << 16);
      }
      uint4* sxp = (uint4*)&SX(row, half * 32);
      uint4* gxp = (uint4*)(x_bf + (size_t)(r0 + row) * DD + kk0 + half * 32);
#pragma unroll
      for (int i = 0; i < 4; ++i) { sxp[i] = pk[i]; gxp[i] = pk[i]; }
    }
    // stage WxT_bf slice (n=row)
    {
      const uint4* wp = (const uint4*)(WxT_bf + (size_t)row * DD + kk0 + half * 32);
      uint4* swp = (uint4*)&SW(row, half * 32);
#pragma unroll
      for (int i = 0; i < 4; ++i) swp[i] = wp[i];
    }
    __syncthreads();
#pragma unroll
    for (int kk = 0; kk < 2; ++kk) {
      frag8 a0 = *(const frag8*)&SX(w * 32 + l15, kk * 32 + quad * 8);
      frag8 a1 = *(const frag8*)&SX(w * 32 + 16 + l15, kk * 32 + quad * 8);
#pragma unroll
      for (int nt = 0; nt < 8; ++nt) {
        frag8 bf = *(const frag8*)&SW(nt * 16 + l15, kk * 32 + quad * 8);
        acc[0][nt] = __builtin_amdgcn_mfma_f32_16x16x32_bf16(a0, bf, acc[0][nt], 0, 0, 0);
        acc[1][nt] = __builtin_amdgcn_mfma_f32_16x16x32_bf16(a1, bf, acc[1][nt], 0, 0, 0);
      }
    }
    __syncthreads();
  }
  // transpose-bounce: sT[a][m] = D[m][a], then write xWT[b][a][t0+m]
#pragma unroll
  for (int mt = 0; mt < 2; ++mt)
#pragma unroll
    for (int nt = 0; nt < 8; ++nt)
#pragma unroll
      for (int r = 0; r < 4; ++r) {
        int m = w * 32 + mt * 16 + quad * 4 + r;
        int a = nt * 16 + l15;
        ST(a, m) = f2bf(acc[mt][nt][r]);
      }
  __syncthreads();
  {
    const uint4* sp = (const uint4*)&ST(row, half * 64);
    uint4* gp = (uint4*)(xWT + ((size_t)bb * AA + row) * TT + t0 + half * 64);
#pragma unroll
    for (int i = 0; i < 8; ++i) gp[i] = sp[i];
  }
#undef SX
#undef SW
#undef ST
}

// ---------- gates: gi/gh dots. grid (6 slices, 32 b), 256 thr ----------
// 16 threads per gate (k-split of 16), coalesced row-segment weight loads,
// width-16 shfl reduce. Each weight element read once per b (L2-hot).
__global__ __launch_bounds__(256) void gates_kernel(
    const float* __restrict__ ctx_acc, const float* __restrict__ den,
    const float* __restrict__ hall, const float* __restrict__ W_ih,
    const float* __restrict__ W_hh, const float* __restrict__ b_ih,
    const float* __restrict__ b_hh, float* __restrict__ gi_buf,
    float* __restrict__ gh_buf, int s) {
  const int slice = blockIdx.x, b = blockIdx.y, tid = threadIdx.x;
  const int kq = tid & 15, gsub = tid >> 4;
  const float invd = 1.0f / den[(s - 1) * BB + b];
  const float4* crow = (const float4*)(ctx_acc + ((size_t)(s - 1) * BB + b) * DD) + kq * 4;
  const float4* hrow = (s >= 2) ? (const float4*)(hall + ((size_t)(s - 2) * BB + b) * HH) + kq * 4 : nullptr;
  float4 c4[4], h4[4];
#pragma unroll
  for (int j = 0; j < 4; ++j) {
    float4 cv = crow[j];
    c4[j].x = cv.x * invd; c4[j].y = cv.y * invd; c4[j].z = cv.z * invd; c4[j].w = cv.w * invd;
    if (hrow) h4[j] = hrow[j];
    else { h4[j].x = 0.f; h4[j].y = 0.f; h4[j].z = 0.f; h4[j].w = 0.f; }
  }
#pragma unroll
  for (int it = 0; it < 8; ++it) {
    const int g = slice * 128 + it * 16 + gsub;
    const float4* wi = (const float4*)(W_ih + (size_t)g * DD) + kq * 4;
    const float4* wh = (const float4*)(W_hh + (size_t)g * HH) + kq * 4;
    float gi = 0.f, gh = 0.f;
#pragma unroll
    for (int j = 0; j < 4; ++j) {
      float4 wv = wi[j];
      gi += c4[j].x * wv.x + c4[j].y * wv.y + c4[j].z * wv.z + c4[j].w * wv.w;
      wv = wh[j];
      gh += h4[j].x * wv.x + h4[j].y * wv.y + h4[j].z * wv.z + h4[j].w * wv.w;
    }
#pragma unroll
    for (int off = 8; off > 0; off >>= 1) {
      gi += __shfl_down(gi, off, 16);
      gh += __shfl_down(gh, off, 16);
    }
    if (kq == 0) {
      gi_buf[b * 768 + g] = gi + b_ih[g];
      gh_buf[b * 768 + g] = gh + b_hh[g];
    }
  }
}

// ---------- h-combine + hWh. grid 32 (b), 256 thr ----------
__global__ __launch_bounds__(256) void hcomb_kernel(
    const float* __restrict__ gi_buf, const float* __restrict__ gh_buf,
    const float* __restrict__ Wh, float* __restrict__ hall,
    float* __restrict__ hWh_buf, int s) {
  const int b = blockIdx.x, i = threadIdx.x;
  __shared__ float sh[HH];
  __shared__ float part[2][AA];
  {
    float gir = gi_buf[b * 768 + i], giz = gi_buf[b * 768 + 256 + i], gin = gi_buf[b * 768 + 512 + i];
    float ghr = gh_buf[b * 768 + i], ghz = gh_buf[b * 768 + 256 + i], ghn = gh_buf[b * 768 + 512 + i];
    float hp = (s >= 2) ? hall[((size_t)(s - 2) * BB + b) * HH + i] : 0.f;
    float r = sigmoid_fast(gir + ghr);
    float z = sigmoid_fast(giz + ghz);
    float n = tanh_fast(gin + r * ghn);
    float hv = (1.f - z) * n + z * hp;
    hall[((size_t)(s - 1) * BB + b) * HH + i] = hv;
    sh[i] = hv;
  }
  __syncthreads();
  {
    const int a = i & 127, kh = i >> 7;
    float acc = 0.f;
#pragma unroll 8
    for (int k = kh * 128; k < kh * 128 + 128; ++k)
      acc = fmaf(sh[k], Wh[k * AA + a], acc);
    part[kh][a] = acc;
  }
  __syncthreads();
  if (i < AA) hWh_buf[b * AA + i] = part[0][i] + part[1][i];
}

// ---------- per-step attention. grid (32 chunks, 32 b), 256 thr ----------
__global__ __launch_bounds__(256) void att_kernel(
    const ushortT* __restrict__ x_bf, const ushortT* __restrict__ xWT_bf,
    const float* __restrict__ hWh_buf, const float* __restrict__ v,
    float* __restrict__ ctx_out, float* __restrict__ den_out) {
  const int tid = threadIdx.x;
  const int chunk = blockIdx.x;  // 0..31, 64 t's each
  const int b = blockIdx.y;
  const int t0 = chunk * 64;
  __shared__ float sh_hWh[AA], sh_v[AA];
  __shared__ float sh_part[8 * 64];
  __shared__ float sh_w[64];
  __shared__ __align__(16) float sh_ctx[4 * DD];
  if (tid < AA) {
    sh_hWh[tid] = hWh_buf ? hWh_buf[b * AA + tid] : 0.f;
    sh_v[tid] = v[tid];
  }
  // Prefetch Phase-B x into regs (independent of scores) so all loads overlap
  const int j4 = tid >> 6, dq = tid & 63;
  ushort4 xr[16];
  {
    const ushort4* xb4 = (const ushort4*)x_bf;
#pragma unroll
    for (int j = 0; j < 16; ++j)
      xr[j] = xb4[(((size_t)(b * TT + t0 + j * 4 + j4)) * DD >> 2) + dq];
  }
  __syncthreads();
  // Phase A: scores. thread = (q = a-group of 16, tp = t-pair)
  {
    const int q = tid >> 5, tp = tid & 31;
    float p0 = 0.f, p1 = 0.f;
    const ushort2* xw2 = (const ushort2*)xWT_bf;
    const size_t base = (size_t)b * (AA * TT / 2) + (t0 >> 1) + tp;
#pragma unroll 4
    for (int i = 0; i < 16; ++i) {
      int a = q * 16 + i;
      ushort2 u = xw2[base + (size_t)a * (TT / 2)];
      float hwa = sh_hWh[a], va = sh_v[a];
      p0 = fmaf(tanh_fast(bf2f(u.x) + hwa), va, p0);
      p1 = fmaf(tanh_fast(bf2f(u.y) + hwa), va, p1);
    }
    sh_part[q * 64 + 2 * tp] = p0;
    sh_part[q * 64 + 2 * tp + 1] = p1;
  }
  __syncthreads();
  if (tid < 64) {
    float e = 0.f;
#pragma unroll
    for (int q = 0; q < 8; ++q) e += sh_part[q * 64 + tid];
    sh_w[tid] = __expf(e);  // |e| <= ||v||_1 ~ 5: no overflow, no max-pass
  }
  __syncthreads();
  // Phase B: ctx partials from prefetched regs
  {
    float4 acc = {0.f, 0.f, 0.f, 0.f};
#pragma unroll
    for (int j = 0; j < 16; ++j) {
      float w = sh_w[j * 4 + j4];
      acc.x = fmaf(w, bf2f(xr[j].x), acc.x);
      acc.y = fmaf(w, bf2f(xr[j].y), acc.y);
      acc.z = fmaf(w, bf2f(xr[j].z), acc.z);
      acc.w = fmaf(w, bf2f(xr[j].w), acc.w);
    }
    ((float4*)sh_ctx)[j4 * 64 + dq] = acc;
  }
  __syncthreads();
  {
    float sum = sh_ctx[tid] + sh_ctx[DD + tid] + sh_ctx[2 * DD + tid] + sh_ctx[3 * DD + tid];
    atomicAdd(&ctx_out[b * DD + tid], sum);
  }
  if (tid < 64) {
    float ds = sh_w[tid];
#pragma unroll
    for (int off = 32; off > 0; off >>= 1) ds += __shfl_down(ds, off, 64);
    if (tid == 0) atomicAdd(&den_out[b], ds);
  }
}

// ---------- final: all logits out[b,s,c] = hall[s,b,:] @ W_cls^T + b_cls ----------
__global__ __launch_bounds__(256) void cls_kernel(
    const float* __restrict__ hall, const float* __restrict__ WclsT,
    const float* __restrict__ b_cls, float* __restrict__ out) {
  const int tid = threadIdx.x;
  const int c0 = blockIdx.x * 128;
  const int r0 = blockIdx.y * 32;
  const int cq = tid & 31, rg = tid >> 5;
  const int c = c0 + cq * 4;
  __shared__ __align__(16) float shh[32 * HH];
  {
    const float4* hsrc = (const float4*)(hall + (size_t)r0 * HH);
    float4* hdst = (float4*)shh;
#pragma unroll
    for (int i = 0; i < 8; ++i) hdst[tid + 256 * i] = hsrc[tid + 256 * i];
  }
  __syncthreads();
  float acc[4][4];
#pragma unroll
  for (int j = 0; j < 4; ++j)
#pragma unroll
    for (int l = 0; l < 4; ++l) acc[j][l] = 0.f;
  for (int k = 0; k < HH; ++k) {
    float4 w4 = *(const float4*)(WclsT + (size_t)k * CLS_LD + c);
    float h0 = shh[(rg * 4 + 0) * HH + k];
    float h1 = shh[(rg * 4 + 1) * HH + k];
    float h2 = shh[(rg * 4 + 2) * HH + k];
    float h3 = shh[(rg * 4 + 3) * HH + k];
    acc[0][0] = fmaf(h0, w4.x, acc[0][0]); acc[0][1] = fmaf(h0, w4.y, acc[0][1]);
    acc[0][2] = fmaf(h0, w4.z, acc[0][2]); acc[0][3] = fmaf(h0, w4.w, acc[0][3]);
    acc[1][0] = fmaf(h1, w4.x, acc[1][0]); acc[1][1] = fmaf(h1, w4.y, acc[1][1]);
    acc[1][2] = fmaf(h1, w4.z, acc[1][2]); acc[1][3] = fmaf(h1, w4.w, acc[1][3]);
    acc[2][0] = fmaf(h2, w4.x, acc[2][0]); acc[2][1] = fmaf(h2, w4.y, acc[2][1]);
    acc[2][2] = fmaf(h2, w4.z, acc[2][2]); acc[2][3] = fmaf(h2, w4.w, acc[2][3]);
    acc[3][0] = fmaf(h3, w4.x, acc[3][0]); acc[3][1] = fmaf(h3, w4.y, acc[3][1]);
    acc[3][2] = fmaf(h3, w4.z, acc[3][2]); acc[3][3] = fmaf(h3, w4.w, acc[3][3]);
  }
#pragma unroll
  for (int j = 0; j < 4; ++j) {
    int row = r0 + rg * 4 + j;  // row = s*BB + b
    int bb = row & (BB - 1), st = row >> 5;
    size_t obase = ((size_t)bb * NSTEPS + st) * CC;
#pragma unroll
    for (int l = 0; l < 4; ++l) {
      int cc = c + l;
      if (cc < CC) out[obase + cc] = acc[j][l] + b_cls[cc];
    }
  }
}

extern "C" void kernel_launch(void* const* d_in, const int* in_sizes, int n_in,
                              void* d_out, int out_size, void* d_ws, size_t ws_size,
                              hipStream_t stream) {
  const float* x     = (const float*)d_in[0];
  const float* Wx    = (const float*)d_in[1];
  const float* Wh    = (const float*)d_in[2];
  const float* v     = (const float*)d_in[3];
  const float* W_ih  = (const float*)d_in[4];
  const float* W_hh  = (const float*)d_in[5];
  const float* b_ih  = (const float*)d_in[6];
  const float* b_hh  = (const float*)d_in[7];
  const float* W_cls = (const float*)d_in[8];
  const float* b_cls = (const float*)d_in[9];
  float* out = (float*)d_out;

  // workspace (~56.6 MiB)
  float* ctx_acc = (float*)d_ws;                            // 22*32*256
  float* den     = ctx_acc + (size_t)NSTEPS * BB * DD;      // 22*32
  float* hWh_buf = den + NSTEPS * BB;                       // 32*128
  float* gi_buf  = hWh_buf + BB * AA;                       // 32*768
  float* gh_buf  = gi_buf + BB * 768;                       // 32*768
  float* hall    = gh_buf + BB * 768;                       // 22*32*256
  float* WclsT   = hall + (size_t)NSTEPS * BB * HH;         // 256*4480
  ushortT* WxT_bf = (ushortT*)(WclsT + (size_t)256 * CLS_LD);  // 128*256
  ushortT* x_bf   = WxT_bf + 128 * 256;                     // BT*256
  ushortT* xWT    = x_bf + (size_t)BB * TT * DD;            // B*A*T

  hipMemsetAsync(ctx_acc, 0, (size_t)(NSTEPS * BB * DD + NSTEPS * BB) * sizeof(float), stream);
  trans_kernel<<<1096 + 32, 256, 0, stream>>>(Wx, W_cls, WclsT, WxT_bf);
  xw_mfma<<<(BB * TT) / 128, 256, 0, stream>>>(x, WxT_bf, x_bf, xWT);

  att_kernel<<<dim3(32, BB), 256, 0, stream>>>(x_bf, xWT, nullptr, v, ctx_acc, den);
  for (int s = 1; s < NSTEPS; ++s) {
    gates_kernel<<<dim3(6, BB), 256, 0, stream>>>(ctx_acc, den, hall, W_ih, W_hh,
                                                  b_ih, b_hh, gi_buf, gh_buf, s);
    hcomb_kernel<<<BB, 256, 0, stream>>>(gi_buf, gh_buf, Wh, hall, hWh_buf, s);
    att_kernel<<<dim3(32, BB), 256, 0, stream>>>(x_bf, xWT, hWh_buf, v,
                                                 ctx_acc + (size_t)s * BB * DD, den + s * BB);
  }
  gates_kernel<<<dim3(6, BB), 256, 0, stream>>>(ctx_acc, den, hall, W_ih, W_hh,
                                                b_ih, b_hh, gi_buf, gh_buf, NSTEPS);
  hcomb_kernel<<<BB, 256, 0, stream>>>(gi_buf, gh_buf, Wh, hall, hWh_buf, NSTEPS);
  cls_kernel<<<dim3(35, 22), 256, 0, stream>>>(hall, WclsT, b_cls, out);
}